// Round 2
// baseline (386.484 us; speedup 1.0000x reference)
//
#include <hip/hip_runtime.h>
#include <hip/hip_cooperative_groups.h>
#include <cstdint>
#include <cstddef>

#define BB 32
#define NN 8400
#define NCC 80
#define MM 40
#define RM 16
#define TOPKK 10
#define CAP 2048      // max positives per (b,m); measured worst case ~450, 4.5x margin
#define SLOTP 41      // LDS stride for per-slot sigmoid tile; gcd(41,32)=1

// ---------- helpers ----------
__device__ __forceinline__ void anchor_xy(int n, float& ax, float& ay) {
    int s, x, y;
    if (n < 6400)      { s = 8;  y = n / 80;            x = n - y * 80; }
    else if (n < 8000) { int i = n - 6400; s = 16; y = i / 40; x = i - y * 40; }
    else               { int i = n - 8000; s = 32; y = i / 20; x = i - y * 20; }
    ax = ((float)x + 0.5f) * (float)s;
    ay = ((float)y + 0.5f) * (float)s;
}

// ---------- K_main: DFL + sigmoid/softplus tile + align + sparse push ----------
// grid: (ceil(N/128), B), 256 threads.
__global__ __launch_bounds__(256) void k_main(const float* __restrict__ ps,
                                              const float* __restrict__ pd,
                                              const int*   __restrict__ gl,
                                              const float* __restrict__ gb,
                                              const float* __restrict__ w,
                                              float* __restrict__ pbb,
                                              float* __restrict__ maxm,
                                              int*   __restrict__ cnts,
                                              unsigned long long* __restrict__ lists,
                                              float* __restrict__ accum,
                                              int*   __restrict__ tgt) {
    __shared__ float  sc[128 * SLOTP];   // sigmoid per (nloc, slot)
    __shared__ float4 box[128];          // ltrb then pred box
    __shared__ float  gtb[MM * 4];
    __shared__ int    glab[MM];
    __shared__ int    slotm[MM];
    __shared__ int    cmap[NCC];
    __shared__ float  cm[256];
    __shared__ float  redf[4];
    const int b  = blockIdx.y;
    const int n0 = blockIdx.x * 128;
    const int t  = threadIdx.x;

    // fused tgt init (replaces a 1 MB memset node); tgt is only read by k_post,
    // which launches after k_main completes -> ordering safe.
    if (t < 128 && n0 + t < NN) tgt[(size_t)b * NN + n0 + t] = 0x7F7F7F7F;

    if (t < MM * 4)              gtb[t] = gb[b * MM * 4 + t];
    if (t >= 192 && t < 192+MM)  glab[t - 192] = gl[b * MM + (t - 192)];
    if (t >= 64 && t < 64+NCC)   cmap[t - 64] = 0x7FFFFFFF;
    __syncthreads();
    if (t < MM) atomicMin(&cmap[glab[t]], t);   // parallel label dedup
    __syncthreads();
    if (t < MM) slotm[t] = cmap[glab[t]];       // slot = representative m, in [0,MM)

    // ---- phase 0: DFL softmax-dot for this block's 128 anchors (512 sides) ----
    #pragma unroll
    for (int h = 0; h < 2; h++) {
        int f = t + h * 256;                    // (anchor,side) flat in [0,512)
        int a = f >> 2, side = f & 3;
        int nc = min(n0 + a, NN - 1);
        const float* p = pd + (((size_t)(b * NN + nc)) * 4 + side) * RM;
        float x[RM];
        #pragma unroll
        for (int i = 0; i < 4; i++) {
            float4 v = *(const float4*)(p + i * 4);
            x[i*4+0] = v.x; x[i*4+1] = v.y; x[i*4+2] = v.z; x[i*4+3] = v.w;
        }
        float mx = x[0];
        #pragma unroll
        for (int i = 1; i < RM; i++) mx = fmaxf(mx, x[i]);
        float s = 0.f, d = 0.f;
        #pragma unroll
        for (int i = 0; i < RM; i++) {
            float e = __builtin_amdgcn_exp2f((x[i] - mx) * 1.44269504f);
            s += e; d += e * w[i];
        }
        ((float*)box)[f] = d * __builtin_amdgcn_rcpf(s);
    }
    __syncthreads();
    if (t < 128) {
        int n = n0 + t;
        float ax, ay; anchor_xy(min(n, NN - 1), ax, ay);
        float4 v = box[t];
        float4 pb = make_float4(ax - v.x, ay - v.y, ax + v.z, ay + v.w);
        box[t] = pb;
        if (n < NN) *(float4*)(pbb + (size_t)(b * NN + n) * 4) = pb;
    }

    // ---- phase 1: 128x80 score tile; batched loads for ILP ----
    float4 vv[10];
    #pragma unroll
    for (int k = 0; k < 10; k++) {
        int f = t + k * 256;                    // [0,2560)
        int row = f / 20, c4 = f - row * 20;
        int nc = min(n0 + row, NN - 1);
        vv[k] = *(const float4*)(ps + ((size_t)(b * NN + nc)) * NCC + c4 * 4);
    }
    float sp = 0.f;
    #pragma unroll
    for (int k = 0; k < 10; k++) {
        int f = t + k * 256;
        int row = f / 20, c4 = f - row * 20;
        float vmask = (n0 + row < NN) ? 1.f : 0.f;
        float xs[4] = {vv[k].x, vv[k].y, vv[k].z, vv[k].w};
        #pragma unroll
        for (int j = 0; j < 4; j++) {
            float x = xs[j];
            float e = __builtin_amdgcn_exp2f(-1.44269504f * fabsf(x));
            float r = __builtin_amdgcn_rcpf(1.0f + e);
            sp += vmask * (fmaxf(x, 0.f) + 0.69314718f * __builtin_amdgcn_logf(1.0f + e));
            int sl = cmap[c4 * 4 + j];
            if (sl < MM) sc[row * SLOTP + sl] = (x >= 0.f) ? r : e * r;
        }
    }
    __syncthreads();

    // ---- phase 2: align for 20 gts per thread-half; push positives; col max ----
    const int nloc = t & 127;
    const int n    = n0 + nloc;
    const int mb   = (t >> 7) * 20;
    const int lane = t & 63;
    const bool valid = (n < NN);
    float cmax = -INFINITY;
    float4 p4 = box[nloc];
    const float px1 = p4.x, py1 = p4.y, px2 = p4.z, py2 = p4.w;
    const float a1 = (px2 - px1) * (py2 - py1);
    #pragma unroll
    for (int j = 0; j < 20; j++) {
        int m = mb + j;
        float gx1 = gtb[m*4+0], gy1 = gtb[m*4+1], gx2 = gtb[m*4+2], gy2 = gtb[m*4+3];
        float a2 = (gx2 - gx1) * (gy2 - gy1);
        float iw = fmaxf(fminf(px2, gx2) - fmaxf(px1, gx1), 0.f);
        float ih = fmaxf(fminf(py2, gy2) - fmaxf(py1, gy1), 0.f);
        float inter = iw * ih;
        float iou = fmaxf(inter * __builtin_amdgcn_rcpf(a1 + a2 - inter + 1e-16f), 0.f);
        float al = 0.f;
        if (valid) {
            float sg = sc[nloc * SLOTP + slotm[m]];
            float i2 = iou * iou;
            al = __builtin_amdgcn_sqrtf(sg) * (i2 * i2 * i2);
        }
        cmax = fmaxf(cmax, al);
        bool pos = valid && (al > 1e-9f);
        unsigned long long msk = __ballot(pos);
        if (msk) {
            int leader = __ffsll((long long)msk) - 1;
            int basev = 0;
            if (lane == leader) basev = atomicAdd(&cnts[b * MM + m], __popcll(msk));
            basev = __shfl(basev, leader);
            if (pos) {
                int ofs = __popcll(msk & ((1ull << lane) - 1ull));
                int idx = basev + ofs;
                if (idx < CAP)
                    lists[((size_t)(b * MM + m)) * CAP + idx] =
                        ((unsigned long long)__float_as_uint(al) << 32) | (unsigned)n;
            }
        }
    }
    cm[t] = cmax;
    __syncthreads();
    if (t < 128 && valid) maxm[(size_t)b * NN + n] = fmaxf(cm[t], cm[t + 128]);

    // softplus block reduction -> one atomic
    #pragma unroll
    for (int off = 32; off > 0; off >>= 1) sp += __shfl_down(sp, off);
    if ((t & 63) == 0) redf[t >> 6] = sp;
    __syncthreads();
    if (t == 0) atomicAdd(accum, redf[0] + redf[1] + redf[2] + redf[3]);
}

// ---------- K_post (cooperative): topk -> grid.sync -> fg -> grid.sync -> final ----------
// grid: B*M = 1280 blocks x 256 threads = 20 waves/CU, co-resident (LDS 16.5KB -> 9 blk/CU cap).
__global__ __launch_bounds__(256, 5) void k_post(const unsigned long long* __restrict__ lists,
                                                 const int*   __restrict__ cnts,
                                                 const float* __restrict__ maxm,
                                                 int*         __restrict__ tgt,
                                                 const int*   __restrict__ gl,
                                                 const float* __restrict__ gb,
                                                 const float* __restrict__ ps,
                                                 const float* __restrict__ pbb,
                                                 float*       __restrict__ accum,
                                                 float*       __restrict__ out) {
    __shared__ unsigned long long keys[CAP];     // 16 KB
    __shared__ unsigned long long sel[TOPKK];
    __shared__ unsigned long long redu[4];
    __shared__ float r[3][4];
    const int t  = threadIdx.x;
    const int bm = blockIdx.x;
    const int b  = bm / MM, m = bm % MM;

    // ---- phase A: top-10 of compacted positives for this (b,m) ----
    int cnt = min(cnts[bm], CAP);
    int kk = min(TOPKK, cnt);
    for (int i = t; i < cnt; i += 256) {
        unsigned long long L = lists[(size_t)bm * CAP + i];
        keys[i] = (L & 0xFFFFFFFF00000000ull) | (0xFFFFFFFFull - (L & 0xFFFFFFFFull));
    }
    __syncthreads();
    for (int p = 0; p < kk; p++) {
        unsigned long long best = 0ull;
        for (int i = t; i < cnt; i += 256) best = keys[i] > best ? keys[i] : best;
        #pragma unroll
        for (int off = 32; off > 0; off >>= 1) {
            unsigned long long o = __shfl_xor(best, off);
            best = o > best ? o : best;
        }
        if ((t & 63) == 0) redu[t >> 6] = best;
        __syncthreads();
        best = redu[0];
        #pragma unroll
        for (int wv = 1; wv < 4; wv++) best = redu[wv] > best ? redu[wv] : best;
        for (int i = t; i < cnt; i += 256) if (keys[i] == best) keys[i] = 0ull;
        if (t == 0) sel[p] = best;
        __syncthreads();
    }
    if (t < kk) {
        unsigned long long sv = sel[t];
        float v = __uint_as_float((unsigned)(sv >> 32));
        int n = (int)(0xFFFFFFFFull - (sv & 0xFFFFFFFFull));
        if (v == maxm[(size_t)b * NN + n]) atomicMin(&tgt[(size_t)b * NN + n], m);
    }

    cooperative_groups::this_grid().sync();

    // ---- phase B: fg accumulation (grid covers B*N) ----
    int i = bm * 256 + t;
    float vdot = 0.f, vbox = 0.f, vfg = 0.f;
    if (i < BB * NN) {
        int tg = tgt[i];
        if (tg < MM) {
            int bb2 = i / NN;
            int lab = gl[bb2 * MM + tg];
            float x = ps[(size_t)i * NCC + lab];
            float mmv = maxm[i];
            float4 p = *(const float4*)(pbb + (size_t)i * 4);
            const float* g = gb + ((size_t)bb2 * MM + tg) * 4;
            float a1 = (p.z - p.x) * (p.w - p.y);
            float a2 = (g[2] - g[0]) * (g[3] - g[1]);
            float iw = fmaxf(fminf(p.z, g[2]) - fmaxf(p.x, g[0]), 0.f);
            float ih = fmaxf(fminf(p.w, g[3]) - fmaxf(p.y, g[1]), 0.f);
            float inter = iw * ih;
            float iou = inter / (a1 + a2 - inter + 1e-16f);
            vdot = x * mmv; vbox = 1.0f - iou; vfg = 1.0f;
        }
    }
    #pragma unroll
    for (int off = 32; off > 0; off >>= 1) {
        vdot += __shfl_down(vdot, off);
        vbox += __shfl_down(vbox, off);
        vfg  += __shfl_down(vfg,  off);
    }
    if ((t & 63) == 0) { int wv = t >> 6; r[0][wv] = vdot; r[1][wv] = vbox; r[2][wv] = vfg; }
    __syncthreads();
    if (t < 3) {
        float s = r[t][0] + r[t][1] + r[t][2] + r[t][3];
        if (s != 0.f) atomicAdd(&accum[1 + t], s);
    }

    cooperative_groups::this_grid().sync();

    // ---- phase C: final scalar ----
    if (bm == 0 && t == 0) {
        float S0  = atomicAdd(&accum[0], 0.f);   // device-scope reads
        float dot = atomicAdd(&accum[1], 0.f);
        float box = atomicAdd(&accum[2], 0.f);
        float fg  = atomicAdd(&accum[3], 0.f);
        float ts = fmaxf(fg, 1.0f);
        float cls = (S0 - dot) / ts;
        float lb = (fg > 0.f) ? box / fg : 0.f;
        out[0] = cls + 1.5f * lb;
    }
}

// ---------- launch ----------
extern "C" void kernel_launch(void* const* d_in, const int* in_sizes, int n_in,
                              void* d_out, int out_size, void* d_ws, size_t ws_size,
                              hipStream_t stream) {
    const float* ps = (const float*)d_in[0];   // pred_scores (B,N,NC)
    const float* pd = (const float*)d_in[1];   // pred_dist   (B,N,64)
    const int*   gl = (const int*)  d_in[2];   // gt_labels   (B,M,1)
    const float* gb = (const float*)d_in[3];   // gt_bboxes   (B,M,4)
    const float* w  = (const float*)d_in[4];   // dfl_weight  (16)

    char* ws = (char*)d_ws;
    constexpr size_t ACC_BYTES  = 256;                                      // accum (8 floats) + pad
    constexpr size_t CNT_BYTES  = 8192;                                     // 1280 ints, padded
    constexpr size_t PBB_BYTES  = (size_t)BB * NN * 4 * sizeof(float);      // 4.30 MB
    constexpr size_t MAXM_BYTES = (size_t)BB * NN * sizeof(float);          // 1.08 MB
    constexpr size_t TGT_BYTES  = (size_t)BB * NN * sizeof(int);            // 1.08 MB

    float* accum = (float*)ws;
    int*   cnts  = (int*)  (ws + ACC_BYTES);
    float* pbb   = (float*)(ws + ACC_BYTES + CNT_BYTES);
    float* maxm  = (float*)(ws + ACC_BYTES + CNT_BYTES + PBB_BYTES);
    int*   tgt   = (int*)  (ws + ACC_BYTES + CNT_BYTES + PBB_BYTES + MAXM_BYTES);
    unsigned long long* lists =
        (unsigned long long*)(ws + ACC_BYTES + CNT_BYTES + PBB_BYTES + MAXM_BYTES + TGT_BYTES);
    float* outp = (float*)d_out;

    // single small memset: accum + cnts contiguous (tgt init is fused into k_main)
    hipMemsetAsync(ws, 0, ACC_BYTES + CNT_BYTES, stream);

    dim3 g3((NN + 127) / 128, BB);
    k_main<<<g3, 256, 0, stream>>>(ps, pd, gl, gb, w, pbb, maxm, cnts, lists, accum, tgt);

    void* args[] = { (void*)&lists, (void*)&cnts, (void*)&maxm, (void*)&tgt, (void*)&gl,
                     (void*)&gb, (void*)&ps, (void*)&pbb, (void*)&accum, (void*)&outp };
    hipLaunchCooperativeKernel((const void*)k_post, dim3(BB * MM), dim3(256), args, 0, stream);
}

// Round 3
// 264.802 us; speedup vs baseline: 1.4595x; 1.4595x over previous
//
#include <hip/hip_runtime.h>
#include <cstdint>
#include <cstddef>

#define BB 32
#define NN 8400
#define NCC 80
#define MM 40
#define RM 16
#define TOPKK 10
#define CAP 2048      // max positives per (b,m); measured worst case ~450, 4.5x margin
#define SLOTP 41      // LDS stride for per-slot sigmoid tile; gcd(41,32)=1
#define CANDMAX 16384 // >= B*M*TOPK = 12800

// ---------- helpers ----------
__device__ __forceinline__ void anchor_xy(int n, float& ax, float& ay) {
    int s, x, y;
    if (n < 6400)      { s = 8;  y = n / 80;            x = n - y * 80; }
    else if (n < 8000) { int i = n - 6400; s = 16; y = i / 40; x = i - y * 40; }
    else               { int i = n - 8000; s = 32; y = i / 20; x = i - y * 20; }
    ax = ((float)x + 0.5f) * (float)s;
    ay = ((float)y + 0.5f) * (float)s;
}

// ---------- K_main: DFL + sigmoid/softplus tile + align + sparse push ----------
// grid: (ceil(N/128), B), 256 threads.
__global__ __launch_bounds__(256) void k_main(const float* __restrict__ ps,
                                              const float* __restrict__ pd,
                                              const int*   __restrict__ gl,
                                              const float* __restrict__ gb,
                                              const float* __restrict__ w,
                                              float* __restrict__ pbb,
                                              float* __restrict__ maxm,
                                              int*   __restrict__ cnts,
                                              unsigned long long* __restrict__ lists,
                                              float* __restrict__ accum,
                                              int*   __restrict__ tgt) {
    __shared__ float  sc[128 * SLOTP];   // sigmoid per (nloc, slot)
    __shared__ float4 box[128];          // ltrb then pred box
    __shared__ float  gtb[MM * 4];
    __shared__ int    glab[MM];
    __shared__ int    slotm[MM];
    __shared__ int    cmap[NCC];
    __shared__ float  cm[256];
    __shared__ float  redf[4];
    const int b  = blockIdx.y;
    const int n0 = blockIdx.x * 128;
    const int t  = threadIdx.x;

    // fused tgt init (replaces a 1 MB memset node); tgt is only read by k_post,
    // which launches after k_main completes -> ordering safe.
    if (t < 128 && n0 + t < NN) tgt[(size_t)b * NN + n0 + t] = 0x7F7F7F7F;

    if (t < MM * 4)              gtb[t] = gb[b * MM * 4 + t];
    if (t >= 192 && t < 192+MM)  glab[t - 192] = gl[b * MM + (t - 192)];
    if (t >= 64 && t < 64+NCC)   cmap[t - 64] = 0x7FFFFFFF;
    __syncthreads();
    if (t < MM) atomicMin(&cmap[glab[t]], t);   // parallel label dedup
    __syncthreads();
    if (t < MM) slotm[t] = cmap[glab[t]];       // slot = representative m, in [0,MM)

    // ---- phase 0: DFL softmax-dot for this block's 128 anchors (512 sides) ----
    #pragma unroll
    for (int h = 0; h < 2; h++) {
        int f = t + h * 256;                    // (anchor,side) flat in [0,512)
        int a = f >> 2, side = f & 3;
        int nc = min(n0 + a, NN - 1);
        const float* p = pd + (((size_t)(b * NN + nc)) * 4 + side) * RM;
        float x[RM];
        #pragma unroll
        for (int i = 0; i < 4; i++) {
            float4 v = *(const float4*)(p + i * 4);
            x[i*4+0] = v.x; x[i*4+1] = v.y; x[i*4+2] = v.z; x[i*4+3] = v.w;
        }
        float mx = x[0];
        #pragma unroll
        for (int i = 1; i < RM; i++) mx = fmaxf(mx, x[i]);
        float s = 0.f, d = 0.f;
        #pragma unroll
        for (int i = 0; i < RM; i++) {
            float e = __builtin_amdgcn_exp2f((x[i] - mx) * 1.44269504f);
            s += e; d += e * w[i];
        }
        ((float*)box)[f] = d * __builtin_amdgcn_rcpf(s);
    }
    __syncthreads();
    if (t < 128) {
        int n = n0 + t;
        float ax, ay; anchor_xy(min(n, NN - 1), ax, ay);
        float4 v = box[t];
        float4 pb = make_float4(ax - v.x, ay - v.y, ax + v.z, ay + v.w);
        box[t] = pb;
        if (n < NN) *(float4*)(pbb + (size_t)(b * NN + n) * 4) = pb;
    }

    // ---- phase 1: 128x80 score tile; batched loads for ILP ----
    float4 vv[10];
    #pragma unroll
    for (int k = 0; k < 10; k++) {
        int f = t + k * 256;                    // [0,2560)
        int row = f / 20, c4 = f - row * 20;
        int nc = min(n0 + row, NN - 1);
        vv[k] = *(const float4*)(ps + ((size_t)(b * NN + nc)) * NCC + c4 * 4);
    }
    float sp = 0.f;
    #pragma unroll
    for (int k = 0; k < 10; k++) {
        int f = t + k * 256;
        int row = f / 20, c4 = f - row * 20;
        float vmask = (n0 + row < NN) ? 1.f : 0.f;
        float xs[4] = {vv[k].x, vv[k].y, vv[k].z, vv[k].w};
        #pragma unroll
        for (int j = 0; j < 4; j++) {
            float x = xs[j];
            float e = __builtin_amdgcn_exp2f(-1.44269504f * fabsf(x));
            float r = __builtin_amdgcn_rcpf(1.0f + e);
            sp += vmask * (fmaxf(x, 0.f) + 0.69314718f * __builtin_amdgcn_logf(1.0f + e));
            int sl = cmap[c4 * 4 + j];
            if (sl < MM) sc[row * SLOTP + sl] = (x >= 0.f) ? r : e * r;
        }
    }
    __syncthreads();

    // ---- phase 2: align for 20 gts per thread-half; push positives; col max ----
    const int nloc = t & 127;
    const int n    = n0 + nloc;
    const int mb   = (t >> 7) * 20;
    const int lane = t & 63;
    const bool valid = (n < NN);
    float cmax = -INFINITY;
    float4 p4 = box[nloc];
    const float px1 = p4.x, py1 = p4.y, px2 = p4.z, py2 = p4.w;
    const float a1 = (px2 - px1) * (py2 - py1);
    #pragma unroll
    for (int j = 0; j < 20; j++) {
        int m = mb + j;
        float gx1 = gtb[m*4+0], gy1 = gtb[m*4+1], gx2 = gtb[m*4+2], gy2 = gtb[m*4+3];
        float a2 = (gx2 - gx1) * (gy2 - gy1);
        float iw = fmaxf(fminf(px2, gx2) - fmaxf(px1, gx1), 0.f);
        float ih = fmaxf(fminf(py2, gy2) - fmaxf(py1, gy1), 0.f);
        float inter = iw * ih;
        float iou = fmaxf(inter * __builtin_amdgcn_rcpf(a1 + a2 - inter + 1e-16f), 0.f);
        float al = 0.f;
        if (valid) {
            float sg = sc[nloc * SLOTP + slotm[m]];
            float i2 = iou * iou;
            al = __builtin_amdgcn_sqrtf(sg) * (i2 * i2 * i2);
        }
        cmax = fmaxf(cmax, al);
        bool pos = valid && (al > 1e-9f);
        unsigned long long msk = __ballot(pos);
        if (msk) {
            int leader = __ffsll((long long)msk) - 1;
            int basev = 0;
            if (lane == leader) basev = atomicAdd(&cnts[b * MM + m], __popcll(msk));
            basev = __shfl(basev, leader);
            if (pos) {
                int ofs = __popcll(msk & ((1ull << lane) - 1ull));
                int idx = basev + ofs;
                if (idx < CAP)
                    lists[((size_t)(b * MM + m)) * CAP + idx] =
                        ((unsigned long long)__float_as_uint(al) << 32) | (unsigned)n;
            }
        }
    }
    cm[t] = cmax;
    __syncthreads();
    if (t < 128 && valid) maxm[(size_t)b * NN + n] = fmaxf(cm[t], cm[t + 128]);

    // softplus block reduction -> one atomic
    #pragma unroll
    for (int off = 32; off > 0; off >>= 1) sp += __shfl_down(sp, off);
    if ((t & 63) == 0) redf[t >> 6] = sp;
    __syncthreads();
    if (t == 0) atomicAdd(accum, redf[0] + redf[1] + redf[2] + redf[3]);
}

// ---------- K_post: topk + sparse candidate push; LAST block does fg + final ----------
// grid: B*M = 1280 blocks x 256 threads. Non-cooperative: no spinning — the last
// block to finish (detected via device-scope done-counter) processes the <=12800
// compact candidates instead of a grid-wide barrier + full B*N scan.
__global__ __launch_bounds__(256) void k_post(const unsigned long long* __restrict__ lists,
                                              const int*   __restrict__ cnts,
                                              const float* __restrict__ maxm,
                                              int*         __restrict__ tgt,
                                              const int*   __restrict__ gl,
                                              const float* __restrict__ gb,
                                              const float* __restrict__ ps,
                                              const float* __restrict__ pbb,
                                              float*       __restrict__ accum,
                                              int*         __restrict__ ctrl,   // [0]=done, [1]=candcnt
                                              unsigned int* __restrict__ cand,
                                              float*       __restrict__ out) {
    __shared__ unsigned long long keys[CAP];     // 16 KB
    __shared__ unsigned long long sel[TOPKK];
    __shared__ unsigned long long redu[4];
    __shared__ float r[3][4];
    __shared__ int lastflag;
    const int t  = threadIdx.x;
    const int bm = blockIdx.x;
    const int b  = bm / MM, m = bm % MM;

    // ---- phase A: top-10 of compacted positives for this (b,m) ----
    int cnt = min(cnts[bm], CAP);
    int kk = min(TOPKK, cnt);
    for (int i = t; i < cnt; i += 256) {
        unsigned long long L = lists[(size_t)bm * CAP + i];
        keys[i] = (L & 0xFFFFFFFF00000000ull) | (0xFFFFFFFFull - (L & 0xFFFFFFFFull));
    }
    __syncthreads();
    for (int p = 0; p < kk; p++) {
        unsigned long long best = 0ull;
        for (int i = t; i < cnt; i += 256) best = keys[i] > best ? keys[i] : best;
        #pragma unroll
        for (int off = 32; off > 0; off >>= 1) {
            unsigned long long o = __shfl_xor(best, off);
            best = o > best ? o : best;
        }
        if ((t & 63) == 0) redu[t >> 6] = best;
        __syncthreads();
        best = redu[0];
        #pragma unroll
        for (int wv = 1; wv < 4; wv++) best = redu[wv] > best ? redu[wv] : best;
        for (int i = t; i < cnt; i += 256) if (keys[i] == best) keys[i] = 0ull;
        if (t == 0) sel[p] = best;
        __syncthreads();
    }
    if (t < kk) {
        unsigned long long sv = sel[t];
        float v = __uint_as_float((unsigned)(sv >> 32));
        int n = (int)(0xFFFFFFFFull - (sv & 0xFFFFFFFFull));
        int idx = b * NN + n;
        if (v == maxm[idx]) {
            atomicMin(&tgt[idx], m);
            int ci = atomicAdd(&ctrl[1], 1);
            if (ci < CANDMAX) cand[ci] = ((unsigned)idx << 6) | (unsigned)m;  // idx<2^19, m<64
        }
    }

    // ---- release: my writes -> device scope, then signal done ----
    __threadfence();
    __syncthreads();
    if (t == 0) {
        int old = atomicAdd(&ctrl[0], 1);
        lastflag = (old == (int)gridDim.x - 1);
    }
    __syncthreads();
    if (!lastflag) return;

    // ---- phase B (last block only): fg accumulation over compact candidates ----
    __threadfence();   // acquire: see all other blocks' tgt/cand writes
    int nc = min(atomicAdd(&ctrl[1], 0), CANDMAX);
    float vdot = 0.f, vbox = 0.f, vfg = 0.f;
    for (int i = t; i < nc; i += 256) {
        unsigned int c = cand[i];
        int m2  = (int)(c & 63u);
        int idx = (int)(c >> 6);
        int tg = __hip_atomic_load(&tgt[idx], __ATOMIC_RELAXED, __HIP_MEMORY_SCOPE_AGENT);
        if (tg == m2) {
            int b2 = idx / NN;
            int lab = gl[b2 * MM + m2];
            float x = ps[(size_t)idx * NCC + lab];
            float mmv = maxm[idx];
            float4 p = *(const float4*)(pbb + (size_t)idx * 4);
            const float* g = gb + ((size_t)b2 * MM + m2) * 4;
            float a1 = (p.z - p.x) * (p.w - p.y);
            float a2 = (g[2] - g[0]) * (g[3] - g[1]);
            float iw = fmaxf(fminf(p.z, g[2]) - fmaxf(p.x, g[0]), 0.f);
            float ih = fmaxf(fminf(p.w, g[3]) - fmaxf(p.y, g[1]), 0.f);
            float inter = iw * ih;
            float iou = inter / (a1 + a2 - inter + 1e-16f);
            vdot += x * mmv; vbox += 1.0f - iou; vfg += 1.0f;
        }
    }
    #pragma unroll
    for (int off = 32; off > 0; off >>= 1) {
        vdot += __shfl_down(vdot, off);
        vbox += __shfl_down(vbox, off);
        vfg  += __shfl_down(vfg,  off);
    }
    if ((t & 63) == 0) { int wv = t >> 6; r[0][wv] = vdot; r[1][wv] = vbox; r[2][wv] = vfg; }
    __syncthreads();

    // ---- phase C: final scalar ----
    if (t == 0) {
        float dot = r[0][0] + r[0][1] + r[0][2] + r[0][3];
        float box = r[1][0] + r[1][1] + r[1][2] + r[1][3];
        float fg  = r[2][0] + r[2][1] + r[2][2] + r[2][3];
        float S0  = accum[0];    // written by k_main (prior kernel boundary)
        float ts = fmaxf(fg, 1.0f);
        float cls = (S0 - dot) / ts;
        float lb = (fg > 0.f) ? box / fg : 0.f;
        out[0] = cls + 1.5f * lb;
    }
}

// ---------- launch ----------
extern "C" void kernel_launch(void* const* d_in, const int* in_sizes, int n_in,
                              void* d_out, int out_size, void* d_ws, size_t ws_size,
                              hipStream_t stream) {
    const float* ps = (const float*)d_in[0];   // pred_scores (B,N,NC)
    const float* pd = (const float*)d_in[1];   // pred_dist   (B,N,64)
    const int*   gl = (const int*)  d_in[2];   // gt_labels   (B,M,1)
    const float* gb = (const float*)d_in[3];   // gt_bboxes   (B,M,4)
    const float* w  = (const float*)d_in[4];   // dfl_weight  (16)

    char* ws = (char*)d_ws;
    constexpr size_t ACC_BYTES  = 256;                                      // accum floats + ctrl ints
    constexpr size_t CNT_BYTES  = 8192;                                     // 1280 ints, padded
    constexpr size_t PBB_BYTES  = (size_t)BB * NN * 4 * sizeof(float);      // 4.30 MB
    constexpr size_t MAXM_BYTES = (size_t)BB * NN * sizeof(float);          // 1.08 MB
    constexpr size_t TGT_BYTES  = (size_t)BB * NN * sizeof(int);            // 1.08 MB
    constexpr size_t LST_BYTES  = (size_t)BB * MM * CAP * 8;                // 20.97 MB

    float* accum = (float*)ws;                         // accum[0..7]
    int*   ctrl  = (int*)  (ws + 64);                  // ctrl[0]=done, ctrl[1]=candcnt
    int*   cnts  = (int*)  (ws + ACC_BYTES);
    float* pbb   = (float*)(ws + ACC_BYTES + CNT_BYTES);
    float* maxm  = (float*)(ws + ACC_BYTES + CNT_BYTES + PBB_BYTES);
    int*   tgt   = (int*)  (ws + ACC_BYTES + CNT_BYTES + PBB_BYTES + MAXM_BYTES);
    unsigned long long* lists =
        (unsigned long long*)(ws + ACC_BYTES + CNT_BYTES + PBB_BYTES + MAXM_BYTES + TGT_BYTES);
    unsigned int* cand =
        (unsigned int*)(ws + ACC_BYTES + CNT_BYTES + PBB_BYTES + MAXM_BYTES + TGT_BYTES + LST_BYTES);
    float* outp = (float*)d_out;

    // single small memset: accum + ctrl + cnts contiguous (tgt init fused into k_main)
    hipMemsetAsync(ws, 0, ACC_BYTES + CNT_BYTES, stream);

    dim3 g3((NN + 127) / 128, BB);
    k_main<<<g3, 256, 0, stream>>>(ps, pd, gl, gb, w, pbb, maxm, cnts, lists, accum, tgt);
    k_post<<<BB * MM, 256, 0, stream>>>(lists, cnts, maxm, tgt, gl, gb, ps, pbb,
                                        accum, ctrl, cand, outp);
}

// Round 4
// 194.330 us; speedup vs baseline: 1.9888x; 1.3626x over previous
//
#include <hip/hip_runtime.h>
#include <cstdint>
#include <cstddef>

#define BB 32
#define NN 8400
#define NCC 80
#define MM 40
#define RM 16
#define TOPKK 10
#define CAP 2048      // max positives per (b,m); measured worst case ~450, 4.5x margin
#define SLOTP 41      // LDS stride for per-slot sigmoid tile; gcd(41,32)=1

// ---------- helpers ----------
__device__ __forceinline__ void anchor_xy(int n, float& ax, float& ay) {
    int s, x, y;
    if (n < 6400)      { s = 8;  y = n / 80;            x = n - y * 80; }
    else if (n < 8000) { int i = n - 6400; s = 16; y = i / 40; x = i - y * 40; }
    else               { int i = n - 8000; s = 32; y = i / 20; x = i - y * 20; }
    ax = ((float)x + 0.5f) * (float)s;
    ay = ((float)y + 0.5f) * (float)s;
}

// ---------- K_main: DFL + sigmoid/softplus tile + align + sparse push ----------
// grid: (ceil(N/128), B), 256 threads.
// T14 async-stage split: all big global loads (pd then ps) are issued together
// right after the cmap barriers; DFL consumes pd while ps is still in flight
// (vmcnt FIFO: waiting on the pd group leaves the ps group outstanding).
__global__ __launch_bounds__(256) void k_main(const float* __restrict__ ps,
                                              const float* __restrict__ pd,
                                              const int*   __restrict__ gl,
                                              const float* __restrict__ gb,
                                              const float* __restrict__ w,
                                              float* __restrict__ pbb,
                                              float* __restrict__ maxm,
                                              int*   __restrict__ cnts,
                                              unsigned long long* __restrict__ lists,
                                              float* __restrict__ accum,
                                              int*   __restrict__ tgt) {
    __shared__ float  sc[128 * SLOTP];   // sigmoid per (nloc, slot)
    __shared__ float4 box[128];          // ltrb then pred box
    __shared__ float  gtb[MM * 4];
    __shared__ int    glab[MM];
    __shared__ int    slotm[MM];
    __shared__ int    cmap[NCC];
    __shared__ float  cm[256];
    __shared__ float  redf[4];
    const int b  = blockIdx.y;
    const int n0 = blockIdx.x * 128;
    const int t  = threadIdx.x;

    // fused tgt init (replaces a 1 MB memset node); tgt only read by later kernels.
    if (t < 128 && n0 + t < NN) tgt[(size_t)b * NN + n0 + t] = 0x7F7F7F7F;

    if (t < MM * 4)              gtb[t] = gb[b * MM * 4 + t];
    if (t >= 192 && t < 192+MM)  glab[t - 192] = gl[b * MM + (t - 192)];
    if (t >= 64 && t < 64+NCC)   cmap[t - 64] = 0x7FFFFFFF;
    __syncthreads();
    if (t < MM) atomicMin(&cmap[glab[t]], t);   // parallel label dedup
    __syncthreads();

    // ---- issue ALL big global loads now (pd first, then ps) ----
    float4 xa[8];                               // pd: 2 (anchor,side) rows x 4 float4
    #pragma unroll
    for (int h = 0; h < 2; h++) {
        int f = t + h * 256;                    // (anchor,side) flat in [0,512)
        int a = f >> 2, side = f & 3;
        int nc = min(n0 + a, NN - 1);
        const float* p = pd + (((size_t)(b * NN + nc)) * 4 + side) * RM;
        #pragma unroll
        for (int i = 0; i < 4; i++) xa[h * 4 + i] = *(const float4*)(p + i * 4);
    }
    float4 vv[10];                              // ps: 128x80 tile
    #pragma unroll
    for (int k = 0; k < 10; k++) {
        int f = t + k * 256;                    // [0,2560)
        int row = f / 20, c4 = f - row * 20;
        int nc = min(n0 + row, NN - 1);
        vv[k] = *(const float4*)(ps + ((size_t)(b * NN + nc)) * NCC + c4 * 4);
    }

    if (t < MM) slotm[t] = cmap[glab[t]];       // slot = representative m, in [0,MM)

    // ---- phase 0: DFL softmax-dot (consumes xa; ps still in flight) ----
    #pragma unroll
    for (int h = 0; h < 2; h++) {
        int f = t + h * 256;
        float x[RM];
        #pragma unroll
        for (int i = 0; i < 4; i++) {
            float4 v = xa[h * 4 + i];
            x[i*4+0] = v.x; x[i*4+1] = v.y; x[i*4+2] = v.z; x[i*4+3] = v.w;
        }
        float mx = x[0];
        #pragma unroll
        for (int i = 1; i < RM; i++) mx = fmaxf(mx, x[i]);
        float s = 0.f, d = 0.f;
        #pragma unroll
        for (int i = 0; i < RM; i++) {
            float e = __builtin_amdgcn_exp2f((x[i] - mx) * 1.44269504f);
            s += e; d += e * w[i];
        }
        ((float*)box)[f] = d * __builtin_amdgcn_rcpf(s);
    }
    __syncthreads();
    if (t < 128) {
        int n = n0 + t;
        float ax, ay; anchor_xy(min(n, NN - 1), ax, ay);
        float4 v = box[t];
        float4 pb = make_float4(ax - v.x, ay - v.y, ax + v.z, ay + v.w);
        box[t] = pb;
        if (n < NN) *(float4*)(pbb + (size_t)(b * NN + n) * 4) = pb;
    }

    // ---- phase 1: sigmoid/softplus on the prefetched 128x80 tile ----
    float sp = 0.f;
    #pragma unroll
    for (int k = 0; k < 10; k++) {
        int f = t + k * 256;
        int row = f / 20, c4 = f - row * 20;
        float vmask = (n0 + row < NN) ? 1.f : 0.f;
        float xs[4] = {vv[k].x, vv[k].y, vv[k].z, vv[k].w};
        #pragma unroll
        for (int j = 0; j < 4; j++) {
            float x = xs[j];
            float e = __builtin_amdgcn_exp2f(-1.44269504f * fabsf(x));
            float r = __builtin_amdgcn_rcpf(1.0f + e);
            sp += vmask * (fmaxf(x, 0.f) + 0.69314718f * __builtin_amdgcn_logf(1.0f + e));
            int sl = cmap[c4 * 4 + j];
            if (sl < MM) sc[row * SLOTP + sl] = (x >= 0.f) ? r : e * r;
        }
    }
    __syncthreads();

    // ---- phase 2: align for 20 gts per thread-half; push positives; col max ----
    const int nloc = t & 127;
    const int n    = n0 + nloc;
    const int mb   = (t >> 7) * 20;
    const int lane = t & 63;
    const bool valid = (n < NN);
    float cmax = -INFINITY;
    float4 p4 = box[nloc];
    const float px1 = p4.x, py1 = p4.y, px2 = p4.z, py2 = p4.w;
    const float a1 = (px2 - px1) * (py2 - py1);
    #pragma unroll
    for (int j = 0; j < 20; j++) {
        int m = mb + j;
        float gx1 = gtb[m*4+0], gy1 = gtb[m*4+1], gx2 = gtb[m*4+2], gy2 = gtb[m*4+3];
        float a2 = (gx2 - gx1) * (gy2 - gy1);
        float iw = fmaxf(fminf(px2, gx2) - fmaxf(px1, gx1), 0.f);
        float ih = fmaxf(fminf(py2, gy2) - fmaxf(py1, gy1), 0.f);
        float inter = iw * ih;
        float iou = fmaxf(inter * __builtin_amdgcn_rcpf(a1 + a2 - inter + 1e-16f), 0.f);
        float al = 0.f;
        if (valid) {
            float sg = sc[nloc * SLOTP + slotm[m]];
            float i2 = iou * iou;
            al = __builtin_amdgcn_sqrtf(sg) * (i2 * i2 * i2);
        }
        cmax = fmaxf(cmax, al);
        bool pos = valid && (al > 1e-9f);
        unsigned long long msk = __ballot(pos);
        if (msk) {
            int leader = __ffsll((long long)msk) - 1;
            int basev = 0;
            if (lane == leader) basev = atomicAdd(&cnts[b * MM + m], __popcll(msk));
            basev = __shfl(basev, leader);
            if (pos) {
                int ofs = __popcll(msk & ((1ull << lane) - 1ull));
                int idx = basev + ofs;
                if (idx < CAP)
                    lists[((size_t)(b * MM + m)) * CAP + idx] =
                        ((unsigned long long)__float_as_uint(al) << 32) | (unsigned)n;
            }
        }
    }
    cm[t] = cmax;
    __syncthreads();
    if (t < 128 && valid) maxm[(size_t)b * NN + n] = fmaxf(cm[t], cm[t + 128]);

    // softplus block reduction -> one atomic
    #pragma unroll
    for (int off = 32; off > 0; off >>= 1) sp += __shfl_down(sp, off);
    if ((t & 63) == 0) redf[t >> 6] = sp;
    __syncthreads();
    if (t == 0) atomicAdd(accum, redf[0] + redf[1] + redf[2] + redf[3]);
}

// ---------- K_topk: top-10 of compacted positives, LDS-only passes ----------
__global__ __launch_bounds__(64) void k_topk(const unsigned long long* __restrict__ lists,
                                             const int*   __restrict__ cnts,
                                             const float* __restrict__ maxm,
                                             int* __restrict__ tgt) {
    __shared__ unsigned long long keys[CAP];
    __shared__ unsigned long long sel[TOPKK];
    const int bm = blockIdx.x, b = bm / MM, m = bm % MM, t = threadIdx.x;
    int cnt = min(cnts[bm], CAP);
    int kk = min(TOPKK, cnt);
    for (int i = t; i < cnt; i += 64) {
        unsigned long long L = lists[(size_t)bm * CAP + i];
        keys[i] = (L & 0xFFFFFFFF00000000ull) | (0xFFFFFFFFull - (L & 0xFFFFFFFFull));
    }
    __syncthreads();
    for (int p = 0; p < kk; p++) {
        unsigned long long best = 0ull;
        for (int i = t; i < cnt; i += 64) best = keys[i] > best ? keys[i] : best;
        #pragma unroll
        for (int off = 32; off > 0; off >>= 1) {
            unsigned long long o = __shfl_xor(best, off);
            best = o > best ? o : best;
        }
        for (int i = t; i < cnt; i += 64) if (keys[i] == best) keys[i] = 0ull;
        if (t == 0) sel[p] = best;
        __syncthreads();
    }
    if (t < kk) {
        unsigned long long bb = sel[t];
        float v = __uint_as_float((unsigned)(bb >> 32));
        int n = (int)(0xFFFFFFFFull - (bb & 0xFFFFFFFFull));
        if (v == maxm[(size_t)b * NN + n]) atomicMin(&tgt[(size_t)b * NN + n], m);
    }
}

// ---------- K_fg: fg accumulation with block reduction ----------
__global__ __launch_bounds__(256) void k_fg(const int*   __restrict__ tgt,
                                            const int*   __restrict__ gl,
                                            const float* __restrict__ gb,
                                            const float* __restrict__ ps,
                                            const float* __restrict__ pbb,
                                            const float* __restrict__ maxm,
                                            float* __restrict__ accum) {
    int i = blockIdx.x * 256 + threadIdx.x;   // i in [0, B*N)
    int t = threadIdx.x;
    float vdot = 0.f, vbox = 0.f, vfg = 0.f;
    int tg = tgt[i];
    if (tg < MM) {
        int b = i / NN;
        int lab = gl[b * MM + tg];
        float x = ps[(size_t)i * NCC + lab];
        float mm = maxm[i];
        float4 p = *(const float4*)(pbb + (size_t)i * 4);
        const float* g = gb + ((size_t)b * MM + tg) * 4;
        float a1 = (p.z - p.x) * (p.w - p.y);
        float a2 = (g[2] - g[0]) * (g[3] - g[1]);
        float iw = fmaxf(fminf(p.z, g[2]) - fmaxf(p.x, g[0]), 0.f);
        float ih = fmaxf(fminf(p.w, g[3]) - fmaxf(p.y, g[1]), 0.f);
        float inter = iw * ih;
        float iou = inter / (a1 + a2 - inter + 1e-16f);
        vdot = x * mm; vbox = 1.0f - iou; vfg = 1.0f;
    }
    #pragma unroll
    for (int off = 32; off > 0; off >>= 1) {
        vdot += __shfl_down(vdot, off);
        vbox += __shfl_down(vbox, off);
        vfg  += __shfl_down(vfg,  off);
    }
    __shared__ float r[3][4];
    if ((t & 63) == 0) { int wv = t >> 6; r[0][wv] = vdot; r[1][wv] = vbox; r[2][wv] = vfg; }
    __syncthreads();
    if (t < 3) {
        float s = r[t][0] + r[t][1] + r[t][2] + r[t][3];
        if (s != 0.f) atomicAdd(&accum[1 + t], s);
    }
}

// ---------- K_final ----------
__global__ void k_final(const float* __restrict__ accum, float* __restrict__ out) {
    float S0 = accum[0], dot = accum[1], box = accum[2], fg = accum[3];
    float ts = fmaxf(fg, 1.0f);
    float cls = (S0 - dot) / ts;
    float lb = (fg > 0.f) ? box / fg : 0.f;
    out[0] = cls + 1.5f * lb;
}

// ---------- launch ----------
extern "C" void kernel_launch(void* const* d_in, const int* in_sizes, int n_in,
                              void* d_out, int out_size, void* d_ws, size_t ws_size,
                              hipStream_t stream) {
    const float* ps = (const float*)d_in[0];   // pred_scores (B,N,NC)
    const float* pd = (const float*)d_in[1];   // pred_dist   (B,N,64)
    const int*   gl = (const int*)  d_in[2];   // gt_labels   (B,M,1)
    const float* gb = (const float*)d_in[3];   // gt_bboxes   (B,M,4)
    const float* w  = (const float*)d_in[4];   // dfl_weight  (16)

    char* ws = (char*)d_ws;
    constexpr size_t ACC_BYTES  = 256;                                      // accum floats + pad
    constexpr size_t CNT_BYTES  = 8192;                                     // 1280 ints, padded
    constexpr size_t PBB_BYTES  = (size_t)BB * NN * 4 * sizeof(float);      // 4.30 MB
    constexpr size_t MAXM_BYTES = (size_t)BB * NN * sizeof(float);          // 1.08 MB
    constexpr size_t TGT_BYTES  = (size_t)BB * NN * sizeof(int);            // 1.08 MB

    float* accum = (float*)ws;
    int*   cnts  = (int*)  (ws + ACC_BYTES);
    float* pbb   = (float*)(ws + ACC_BYTES + CNT_BYTES);
    float* maxm  = (float*)(ws + ACC_BYTES + CNT_BYTES + PBB_BYTES);
    int*   tgt   = (int*)  (ws + ACC_BYTES + CNT_BYTES + PBB_BYTES + MAXM_BYTES);
    unsigned long long* lists =
        (unsigned long long*)(ws + ACC_BYTES + CNT_BYTES + PBB_BYTES + MAXM_BYTES + TGT_BYTES);

    // single small memset: accum + cnts contiguous (tgt init fused into k_main)
    hipMemsetAsync(ws, 0, ACC_BYTES + CNT_BYTES, stream);

    dim3 g3((NN + 127) / 128, BB);
    k_main<<<g3, 256, 0, stream>>>(ps, pd, gl, gb, w, pbb, maxm, cnts, lists, accum, tgt);
    k_topk<<<BB * MM, 64, 0, stream>>>(lists, cnts, maxm, tgt);
    k_fg<<<BB * NN / 256, 256, 0, stream>>>(tgt, gl, gb, ps, pbb, maxm, accum);
    k_final<<<1, 1, 0, stream>>>(accum, (float*)d_out);
}